// Round 5
// baseline (266.292 us; speedup 1.0000x reference)
//
#include <hip/hip_runtime.h>

// GAT_gate: B=8, N=2048, D=128
// out = c*x + (1-c)*relu(att@h), att = colsoftmax(mask(hA h^T + h hA^T))*adj
// e small (|e|<~6) -> exp without max-subtraction (clamp 60).
// cat[n][0:128]=hA[n], cat[n][128:256]=h[n]; e[i,j] = cat[i] . catsw[j].
// R14 = R13 tiling + counted-vmcnt barriers (guide T4) in k2 AND k3.
//  R13 post-mortem: neutral (265us) because __syncthreads = vmcnt(0) drain
//  re-serialized the dbuf pipeline at every barrier. Fix: raw s_barrier +
//  counted s_waitcnt so next-tile loads stay in flight across barriers:
//   k3: 10 GLL/wave/tile -> vmcnt(10) steady, vmcnt(0) last; 2x40KB dbuf.
//   k2: per wave/tile 8 GLL + 16 adj loads + 16 pun stores ->
//       vmcnt(40) retires GLL(t)+ADJ(t), leaves stores(t-1)+stage(t+1)
//       flying; last tile vmcnt(16). Counts audited incl. iter0 and
//       intra-phase compiler reorder (asm "memory" bounds each phase).
//  Buffer-overwrite safety: stage(t+2->buf[t&1]) is issued only after the
//  trailing s_barrier that all waves cross after finishing compute(t)'s
//  LDS reads (every ds_read's MFMA use precedes the barrier -> lgkm done).
// Numerics bit-identical to R13 (same ops, same order per element).

#define B_ 8
#define N_ 2048
#define D_ 128

typedef __attribute__((ext_vector_type(8))) short short8;
typedef __attribute__((ext_vector_type(4))) float f32x4;
typedef __attribute__((ext_vector_type(2))) float f32x2;

#define GLL(gp, lp) __builtin_amdgcn_global_load_lds( \
    (__attribute__((address_space(1))) const unsigned int*)(gp), \
    (__attribute__((address_space(3))) unsigned int*)(lp), 16, 0, 0)

#define VMW(N) asm volatile("s_waitcnt vmcnt(" #N ")" ::: "memory")
#define BARRIER() __builtin_amdgcn_s_barrier()

static __device__ __forceinline__ unsigned short f2bf(float f) {
  union { float f; unsigned int u; } v; v.f = f;
  unsigned int r = v.u + 0x7fffu + ((v.u >> 16) & 1u);
  return (unsigned short)(r >> 16);
}
static __device__ __forceinline__ float bf2f(unsigned short u) {
  union { unsigned int u; float f; } v; v.u = ((unsigned int)u) << 16;
  return v.f;
}

// ---- workspace layout (bytes) ----
#define CAT_OFF  ((size_t)0)         // bf16 cat [B][N][256]        8 MB
#define VT_OFF   ((size_t)8388608)   // bf16 V'^T [B][128][N]       4 MB
#define PUN_OFF  ((size_t)12582912)  // bf16 P_un [B][N][N]         67.1 MB
#define S_OFF    ((size_t)79691776)  // f32 colsum s [B][N]         64 KB
#define WB_OFF   ((size_t)79757312)  // bf16 W [128][128]           32 KB
#define AT_OFF   ((size_t)79790080)  // bf16 A^T [128][128]         32 KB

// ---------- prep: W -> bf16 (same layout), A -> bf16 transposed ----------
__global__ __launch_bounds__(256) void k_cvt(const float* __restrict__ W,
                                             const float* __restrict__ A,
                                             unsigned short* __restrict__ Wb1,
                                             unsigned short* __restrict__ Abt) {
  int i = blockIdx.x * 256 + threadIdx.x;   // grid 64 blocks covers 128*128
  Wb1[i] = f2bf(W[i]);
  Abt[(i & 127) * 128 + (i >> 7)] = f2bf(A[i]);
}

// ---------- k1: h = x@W^T + b, hA = h@A via MFMA; write cat bf16 ----------
// grid 256 blocks; 4 waves; wave w owns rows blockIdx.x*64 + w*16 .. +16.
__global__ __launch_bounds__(256) void k1(const float* __restrict__ x,
                                          const unsigned short* __restrict__ Wb1,
                                          const float* __restrict__ Wbias,
                                          const unsigned short* __restrict__ Abt,
                                          unsigned short* __restrict__ cat) {
  __shared__ unsigned short hsm[4][16][136];   // 272 B rows, 16B-aligned
  __shared__ unsigned short hasm[4][16][136];
  const int t = threadIdx.x, w = t >> 6, lane = t & 63;
  const int q = lane >> 4, l15 = lane & 15;
  const size_t r0 = (size_t)blockIdx.x * 64 + w * 16;

  f32x4 acc[8];
#pragma unroll
  for (int dg = 0; dg < 8; dg++) acc[dg] = (f32x4){0.f, 0.f, 0.f, 0.f};
  // GEMM1: h = x @ W^T  (B[k=f][col=d] = W[d][f], contiguous in f)
#pragma unroll
  for (int k = 0; k < 4; k++) {
    const float* xp = x + (r0 + l15) * 128 + k * 32 + q * 8;
    f32x4 xa = *(const f32x4*)xp;
    f32x4 xb = *(const f32x4*)(xp + 4);
    short8 af;
#pragma unroll
    for (int e = 0; e < 4; e++) { af[e] = (short)f2bf(xa[e]); af[4 + e] = (short)f2bf(xb[e]); }
#pragma unroll
    for (int dg = 0; dg < 8; dg++) {
      short8 bf = *(const short8*)(Wb1 + (dg * 16 + l15) * 128 + k * 32 + q * 8);
      acc[dg] = __builtin_amdgcn_mfma_f32_16x16x32_bf16(af, bf, acc[dg], 0, 0, 0);
    }
  }
#pragma unroll
  for (int dg = 0; dg < 8; dg++) {
    float bias = Wbias[dg * 16 + l15];
#pragma unroll
    for (int r = 0; r < 4; r++)
      hsm[w][q * 4 + r][dg * 16 + l15] = f2bf(acc[dg][r] + bias);
  }
  __syncthreads();
  // GEMM2: hA = h @ A  (B[k=d][col=e] = A[d][e] = Abt[e][d], contiguous in d)
  f32x4 acc2[8];
#pragma unroll
  for (int dg = 0; dg < 8; dg++) acc2[dg] = (f32x4){0.f, 0.f, 0.f, 0.f};
#pragma unroll
  for (int k = 0; k < 4; k++) {
    short8 af = *(short8*)&hsm[w][l15][k * 32 + q * 8];
#pragma unroll
    for (int dg = 0; dg < 8; dg++) {
      short8 bf = *(const short8*)(Abt + (dg * 16 + l15) * 128 + k * 32 + q * 8);
      acc2[dg] = __builtin_amdgcn_mfma_f32_16x16x32_bf16(af, bf, acc2[dg], 0, 0, 0);
    }
  }
#pragma unroll
  for (int dg = 0; dg < 8; dg++)
#pragma unroll
    for (int r = 0; r < 4; r++)
      hasm[w][q * 4 + r][dg * 16 + l15] = f2bf(acc2[dg][r]);
  __syncthreads();
  // store cat: cols 0..127 = hA, cols 128..255 = h
#pragma unroll
  for (int it = 0; it < 8; it++) {
    int idx = it * 64 + lane;
    int row = idx >> 5, c = idx & 31;
    short8 v = (c < 16) ? *(short8*)&hasm[w][row][c * 8]
                        : *(short8*)&hsm[w][row][(c - 16) * 8];
    *(short8*)(cat + ((r0 + row) << 8) + c * 8) = v;
  }
}

// ---------- k2: E once; s[k] += mask*exp(E); P_un packed-pair bf16 ----------
// grid (16, 4, B); 4 waves; wave w owns k-cols [kbase+w*32, +32), lane pair
// cols kc+2*l15, kc+2*l15+1. Block sweeps 8 j-tiles of 64 rows; 2-phase
// dbuf with COUNTED vmcnt barriers (next-tile loads fly across barriers).
__global__ __launch_bounds__(256, 2) void k2(const unsigned short* __restrict__ cat,
                                             const float* __restrict__ adj,
                                             unsigned short* __restrict__ pun,
                                             float* __restrict__ s_out) {
  __shared__ unsigned short cj[2][64 * 256];  // 2 x 32 KB, XOR-swizzled chunks
  const int t = threadIdx.x, w = t >> 6, lane = t & 63;
  const int q = lane >> 4, l15 = lane & 15;
  const int b = blockIdx.z;
  const int kbase = blockIdx.x * 128;
  const int j0b = blockIdx.y * 512;           // 8 tiles of 64 rows
  const size_t bN = (size_t)b * N_;
  const unsigned short* catp = cat + (bN << 8);
  const int kc = kbase + w * 32;
  short8 brg[2][8];  // catsw_k fragments for cols kc+2*l15+p (swap +16 mod 32)
#pragma unroll
  for (int p = 0; p < 2; p++) {
    int krow = kc + 2 * l15 + p;
#pragma unroll
    for (int m = 0; m < 8; m++)
      brg[p][m] = *(const short8*)(catp + (((size_t)krow) << 8) +
                                   ((((m * 4 + q) + 16) & 31) * 8));
  }
  float acc0 = 0.f, acc1 = 0.f;

#define K2_STAGE(tt, bufi) do { \
    const int j0_ = j0b + (tt) * 64; \
    _Pragma("unroll") \
    for (int it = 0; it < 8; it++) { \
      int sI = it * 256 + t; \
      int row = sI >> 5, c = sI & 31; \
      GLL(catp + (((size_t)(j0_ + row)) << 8) + (c ^ (row & 7)) * 8, \
          (char*)cj[bufi] + sI * 16); \
    } } while (0)

#define K2_ADJ(tt, av) do { \
    const int j0_ = j0b + (tt) * 64; \
    _Pragma("unroll") \
    for (int js = 0; js < 4; js++) \
      _Pragma("unroll") \
      for (int r = 0; r < 4; r++) { \
        int jrow = j0_ + js * 16 + q * 4 + r; \
        av[js][r] = *(const f32x2*)(adj + (((size_t)(bN + jrow)) << 11) + kc + 2 * l15); \
      } } while (0)

#define K2_COMPUTE(tt, bufi, av) do { \
    const int j0_ = j0b + (tt) * 64; \
    _Pragma("unroll") \
    for (int jsub = 0; jsub < 4; jsub++) { \
      const int row = jsub * 16 + l15; \
      short8 afr[8]; \
      _Pragma("unroll") \
      for (int m = 0; m < 8; m++) \
        afr[m] = *(short8*)(cj[bufi] + row * 256 + (((m * 4 + q) ^ (l15 & 7)) * 8)); \
      f32x4 e0 = {0.f, 0.f, 0.f, 0.f}, e1 = {0.f, 0.f, 0.f, 0.f}; \
      _Pragma("unroll") \
      for (int m = 0; m < 8; m++) { \
        e0 = __builtin_amdgcn_mfma_f32_16x16x32_bf16(afr[m], brg[0][m], e0, 0, 0, 0); \
        e1 = __builtin_amdgcn_mfma_f32_16x16x32_bf16(afr[m], brg[1][m], e1, 0, 0, 0); \
      } \
      _Pragma("unroll") \
      for (int r = 0; r < 4; r++) { \
        int jrow = j0_ + jsub * 16 + q * 4 + r; \
        float x0 = (av[jsub][r][0] > 0.f) ? __expf(fminf(e0[r], 60.f)) : 0.f; \
        float x1 = (av[jsub][r][1] > 0.f) ? __expf(fminf(e1[r], 60.f)) : 0.f; \
        acc0 += x0; acc1 += x1; \
        unsigned int pk = (unsigned int)f2bf(x0) | ((unsigned int)f2bf(x1) << 16); \
        *(unsigned int*)(pun + ((bN + jrow) << 11) + kc + 2 * l15) = pk; \
      } \
    } } while (0)

  f32x2 avA[4][4], avB[4][4];
  // prologue: stage tile 0
  K2_STAGE(0, 0);
  K2_ADJ(0, avA);
#pragma unroll
  for (int tp = 0; tp < 4; tp++) {
    // even tile 2*tp: stage 2*tp+1 -> buf1/avB, compute buf0/avA
    K2_STAGE(2 * tp + 1, 1);
    K2_ADJ(2 * tp + 1, avB);
    VMW(40);            // GLL(t)+ADJ(t) retired; stores(t-1)+stage(t+1) fly
    BARRIER();
    K2_COMPUTE(2 * tp, 0, avA);
    BARRIER();          // protect cj[0] before next stage overwrites it
    // odd tile 2*tp+1: stage 2*tp+2 -> buf0/avA, compute buf1/avB
    if (2 * tp + 2 < 8) {
      K2_STAGE(2 * tp + 2, 0);
      K2_ADJ(2 * tp + 2, avA);
      VMW(40);
    } else {
      VMW(16);          // last tile: only stores(6) may remain in flight
    }
    BARRIER();
    K2_COMPUTE(2 * tp + 1, 1, avB);
    BARRIER();
  }
#undef K2_STAGE
#undef K2_ADJ
#undef K2_COMPUTE

  acc0 += __shfl_xor(acc0, 16, 64); acc0 += __shfl_xor(acc0, 32, 64);
  acc1 += __shfl_xor(acc1, 16, 64); acc1 += __shfl_xor(acc1, 32, 64);
  if (lane < 16) {
    atomicAdd(&s_out[bN + kc + 2 * lane], acc0);
    atomicAdd(&s_out[bN + kc + 2 * lane + 1], acc1);
  }
}

// ---------- k1v: vt[b][d][j] = bf16(h[b][j][d] / s[j]) (R4-proven) ----------
__global__ __launch_bounds__(256) void k1v(const unsigned short* __restrict__ cat,
                                           const float* __restrict__ s,
                                           unsigned short* __restrict__ vt) {
  __shared__ unsigned short tile[64][136];
  __shared__ float rsv[64];
  const int t = threadIdx.x;
  const int b = blockIdx.y;
  const int nbase = blockIdx.x * 64;
  if (t < 64) rsv[t] = 1.f / s[(size_t)b * N_ + nbase + t];
#pragma unroll
  for (int k = 0; k < 4; k++) {
    int sI = t + 256 * k;
    int row = sI >> 4, part = sI & 15;
    *(short8*)&tile[row][part * 8] =
        *(const short8*)(cat + (((size_t)(b * N_ + nbase + row)) << 8) + 128 + part * 8);
  }
  __syncthreads();
#pragma unroll
  for (int k = 0; k < 4; k++) {
    int sI = t + 256 * k;
    int dd = sI >> 3, part = sI & 7;
    unsigned short tmp[8];
#pragma unroll
    for (int j = 0; j < 8; j++) {
      int jj = part * 8 + j;
      tmp[j] = f2bf(bf2f(tile[jj][dd]) * rsv[jj]);
    }
    *(short8*)(vt + (((size_t)(b * 128 + dd)) << 11) + nbase + part * 8) = *(short8*)tmp;
  }
}

// ---------- k3: h' = P_un @ V'; out = c*x + (1-c)*relu(h') ----------
// grid (N/32, B); 4 waves; wave w owns d-group [w*32, w*32+32); j-tile 128.
// 2x40KB dbuf, counted vmcnt(10) barriers: tile t+1's 10 GLL fly across
// the barriers and the whole compute(t).
__global__ __launch_bounds__(256) void k3(const unsigned short* __restrict__ pun,
                                          const unsigned short* __restrict__ vt,
                                          const float* __restrict__ x,
                                          const float* __restrict__ gw,
                                          const float* __restrict__ gb,
                                          float* __restrict__ out) {
  __shared__ char smem[2][40960];
  // per buffer: [0,8192): A-tile P_un 32 x 128j  [8192,40960): B-tile vt 128d x 128j
  const int t = threadIdx.x, w = t >> 6, lane = t & 63;
  const int q = lane >> 4, l15 = lane & 15;
  const int b = blockIdx.y, i0 = blockIdx.x * 32;
  const size_t bN = (size_t)b * N_;

  f32x4 acc[2][2];
#pragma unroll
  for (int ih = 0; ih < 2; ih++)
#pragma unroll
    for (int dh = 0; dh < 2; dh++) acc[ih][dh] = (f32x4){0.f, 0.f, 0.f, 0.f};

#define K3_STAGE(jtv, bufi) do { \
    const int j0_ = (jtv) * 128; \
    _Pragma("unroll") \
    for (int it = 0; it < 10; it++) { \
      int sI = it * 256 + t; \
      const unsigned short* g; \
      if (sI < 512) { \
        int row = sI >> 4, c = sI & 15; \
        g = pun + (((size_t)(bN + i0 + row)) << 11) + j0_ + ((c ^ (row & 7)) * 8); \
      } else { \
        int s2 = sI - 512; \
        int dd = s2 >> 4, c = s2 & 15; \
        g = vt + (((size_t)(b * 128 + dd)) << 11) + j0_ + ((c ^ (dd & 7)) * 8); \
      } \
      GLL(g, smem[bufi] + sI * 16); \
    } } while (0)

#define K3_COMPUTE(bufi) do { \
    unsigned short* pa = (unsigned short*)smem[bufi]; \
    unsigned short* vb = (unsigned short*)(smem[bufi] + 8192); \
    _Pragma("unroll") \
    for (int ks = 0; ks < 4; ks++) { \
      short8 af[2], bf[2]; \
      _Pragma("unroll") \
      for (int ih = 0; ih < 2; ih++) { \
        int m = ih * 16 + l15; \
        af[ih] = *(short8*)(pa + m * 128 + (((ks * 4 + q) ^ (m & 7)) * 8)); \
      } \
      _Pragma("unroll") \
      for (int dh = 0; dh < 2; dh++) { \
        int d = w * 32 + dh * 16 + l15; \
        bf[dh] = *(short8*)(vb + d * 128 + (((ks * 4 + q) ^ (d & 7)) * 8)); \
      } \
      acc[0][0] = __builtin_amdgcn_mfma_f32_16x16x32_bf16(af[0], bf[0], acc[0][0], 0, 0, 0); \
      acc[0][1] = __builtin_amdgcn_mfma_f32_16x16x32_bf16(af[0], bf[1], acc[0][1], 0, 0, 0); \
      acc[1][0] = __builtin_amdgcn_mfma_f32_16x16x32_bf16(af[1], bf[0], acc[1][0], 0, 0, 0); \
      acc[1][1] = __builtin_amdgcn_mfma_f32_16x16x32_bf16(af[1], bf[1], acc[1][1], 0, 0, 0); \
    } } while (0)

  K3_STAGE(0, 0);
  for (int jt = 0; jt < 15; jt++) {
    K3_STAGE(jt + 1, (jt + 1) & 1);
    asm volatile("s_waitcnt vmcnt(10)" ::: "memory");
    BARRIER();
    K3_COMPUTE(jt & 1);
    BARRIER();
  }
  asm volatile("s_waitcnt vmcnt(0)" ::: "memory");
  BARRIER();
  K3_COMPUTE(1);   // jt = 15
  __syncthreads(); // all reads done before epilogue reuses smem[0]
#undef K3_STAGE
#undef K3_COMPUTE

  // epilogue: relu -> LDS f32, gate, sigmoid, blend, store
  float* hs = (float*)smem[0];            // 32 x 132 f32 = 16896 B
  float* co = (float*)(smem[0] + 16896);  // 32 f32
#pragma unroll
  for (int ih = 0; ih < 2; ih++)
#pragma unroll
    for (int dh = 0; dh < 2; dh++)
#pragma unroll
      for (int r = 0; r < 4; r++) {
        int row = ih * 16 + q * 4 + r;
        int d = w * 32 + dh * 16 + l15;
        hs[row * 132 + d] = fmaxf(acc[ih][dh][r], 0.f);
      }
  __syncthreads();
  {
    int grow = t >> 3, sub = t & 7;
    const float* xr = x + (((size_t)(bN + i0 + grow)) << 7);
    float z = 0.f;
#pragma unroll
    for (int k = 0; k < 16; k++) {
      int dd = sub + 8 * k;
      z += gw[dd] * xr[dd] + gw[128 + dd] * hs[grow * 132 + dd];
    }
    z += __shfl_xor(z, 1, 64);
    z += __shfl_xor(z, 2, 64);
    z += __shfl_xor(z, 4, 64);
    if (sub == 0) co[grow] = 1.f / (1.f + __expf(-(z + gb[0])));
  }
  __syncthreads();
#pragma unroll
  for (int kk = 0; kk < 4; kk++) {
    int id = kk * 256 + t;
    int row = id >> 5, c4 = id & 31;
    size_t g = (((size_t)(bN + i0 + row)) << 7) + c4 * 4;
    f32x4 xv = *(const f32x4*)(x + g);
    f32x4 hv = *(const f32x4*)(hs + row * 132 + c4 * 4);
    float cf = co[row];
    f32x4 o;
#pragma unroll
    for (int e = 0; e < 4; e++) o[e] = cf * xv[e] + (1.f - cf) * hv[e];
    *(f32x4*)(out + g) = o;
  }
}

extern "C" void kernel_launch(void* const* d_in, const int* in_sizes, int n_in,
                              void* d_out, int out_size, void* d_ws, size_t ws_size,
                              hipStream_t stream) {
  const float* x   = (const float*)d_in[0];
  const float* adj = (const float*)d_in[1];
  const float* Ww  = (const float*)d_in[2];
  const float* Wb  = (const float*)d_in[3];
  const float* A   = (const float*)d_in[4];
  const float* gw  = (const float*)d_in[5];
  const float* gb  = (const float*)d_in[6];
  float* out = (float*)d_out;
  char* ws = (char*)d_ws;

  unsigned short* cat = (unsigned short*)(ws + CAT_OFF);
  unsigned short* vt  = (unsigned short*)(ws + VT_OFF);
  unsigned short* pun = (unsigned short*)(ws + PUN_OFF);
  float* s  = (float*)(ws + S_OFF);
  unsigned short* Wb1 = (unsigned short*)(ws + WB_OFF);
  unsigned short* Abt = (unsigned short*)(ws + AT_OFF);

  hipMemsetAsync(s, 0, (size_t)B_ * N_ * sizeof(float), stream);
  k_cvt<<<64, 256, 0, stream>>>(Ww, A, Wb1, Abt);
  k1<<<(B_ * N_) / 64, 256, 0, stream>>>(x, Wb1, Wb, Abt, cat);
  k2<<<dim3(16, 4, B_), 256, 0, stream>>>(cat, adj, pun, s);
  k1v<<<dim3(N_ / 64, B_), 256, 0, stream>>>(cat, s, vt);
  k3<<<dim3(N_ / 32, B_), 256, 0, stream>>>(pun, vt, x, gw, gb, out);
}

// Round 6
// 263.726 us; speedup vs baseline: 1.0097x; 1.0097x over previous
//
#include <hip/hip_runtime.h>

// GAT_gate: B=8, N=2048, D=128
// out = c*x + (1-c)*relu(att@h), att = colsoftmax(mask(hA h^T + h hA^T))*adj
// e small (|e|<~6) -> exp without max-subtraction (clamp 60).
// cat[n][0:128]=hA[n], cat[n][128:256]=h[n]; e[i,j] = cat[i] . catsw[j].
// R15: k2 rebuilt to mirror k3's PROVEN counted-vmcnt structure.
//  R14 post-mortem: k3 (GLL-only loop VMEM) improved ~75->~40us with counted
//  vmcnt; k2 regressed 78->128us because its adj loads land in VGPRs and the
//  compiler's waitcnt pass, unable to track them across inline asm, inserted
//  a conservative vmcnt(0) before every av use (also masking a VMW(40)
//  miscount at tp=0). Fix: NO VGPR-landing VMEM in k2's loop. j-tile
//  shrunk to 32 rows so adj ALSO stages via GLL: per buffer cat 16KB +
//  adj 16KB; dbuf = 64KB LDS -> 2 blocks/CU. Per wave per tile: 8 GLL
//  (4 cat + 4 adj) + 8 pun stores.
//  vmcnt ledger (per wave, in order): S(t)[8], st(t-1)[8], S(t+1)[8].
//   steady: retire S(t) -> VMW(16). tp=0: S(0)[8],S(1)[8] -> VMW(8).
//   final:  S(15)[8], st(14)[8] -> VMW(8).
//  adj LDS swizzle = R11's proven formula (read chunk (w*8+(l15>>1))^(jr&7)).
// k3 kept from R14 (counted vmcnt, 2x40KB dbuf). Numerics bit-identical.

#define B_ 8
#define N_ 2048
#define D_ 128

typedef __attribute__((ext_vector_type(8))) short short8;
typedef __attribute__((ext_vector_type(4))) float f32x4;
typedef __attribute__((ext_vector_type(2))) float f32x2;

#define GLL(gp, lp) __builtin_amdgcn_global_load_lds( \
    (__attribute__((address_space(1))) const unsigned int*)(gp), \
    (__attribute__((address_space(3))) unsigned int*)(lp), 16, 0, 0)

#define VMW(N) asm volatile("s_waitcnt vmcnt(" #N ")" ::: "memory")
#define BARRIER() __builtin_amdgcn_s_barrier()

static __device__ __forceinline__ unsigned short f2bf(float f) {
  union { float f; unsigned int u; } v; v.f = f;
  unsigned int r = v.u + 0x7fffu + ((v.u >> 16) & 1u);
  return (unsigned short)(r >> 16);
}
static __device__ __forceinline__ float bf2f(unsigned short u) {
  union { unsigned int u; float f; } v; v.u = ((unsigned int)u) << 16;
  return v.f;
}

// ---- workspace layout (bytes) ----
#define CAT_OFF  ((size_t)0)         // bf16 cat [B][N][256]        8 MB
#define VT_OFF   ((size_t)8388608)   // bf16 V'^T [B][128][N]       4 MB
#define PUN_OFF  ((size_t)12582912)  // bf16 P_un [B][N][N]         67.1 MB
#define S_OFF    ((size_t)79691776)  // f32 colsum s [B][N]         64 KB
#define WB_OFF   ((size_t)79757312)  // bf16 W [128][128]           32 KB
#define AT_OFF   ((size_t)79790080)  // bf16 A^T [128][128]         32 KB

// ---------- prep: W -> bf16 (same layout), A -> bf16 transposed ----------
__global__ __launch_bounds__(256) void k_cvt(const float* __restrict__ W,
                                             const float* __restrict__ A,
                                             unsigned short* __restrict__ Wb1,
                                             unsigned short* __restrict__ Abt) {
  int i = blockIdx.x * 256 + threadIdx.x;   // grid 64 blocks covers 128*128
  Wb1[i] = f2bf(W[i]);
  Abt[(i & 127) * 128 + (i >> 7)] = f2bf(A[i]);
}

// ---------- k1: h = x@W^T + b, hA = h@A via MFMA; write cat bf16 ----------
// grid 256 blocks; 4 waves; wave w owns rows blockIdx.x*64 + w*16 .. +16.
__global__ __launch_bounds__(256) void k1(const float* __restrict__ x,
                                          const unsigned short* __restrict__ Wb1,
                                          const float* __restrict__ Wbias,
                                          const unsigned short* __restrict__ Abt,
                                          unsigned short* __restrict__ cat) {
  __shared__ unsigned short hsm[4][16][136];   // 272 B rows, 16B-aligned
  __shared__ unsigned short hasm[4][16][136];
  const int t = threadIdx.x, w = t >> 6, lane = t & 63;
  const int q = lane >> 4, l15 = lane & 15;
  const size_t r0 = (size_t)blockIdx.x * 64 + w * 16;

  f32x4 acc[8];
#pragma unroll
  for (int dg = 0; dg < 8; dg++) acc[dg] = (f32x4){0.f, 0.f, 0.f, 0.f};
  // GEMM1: h = x @ W^T  (B[k=f][col=d] = W[d][f], contiguous in f)
#pragma unroll
  for (int k = 0; k < 4; k++) {
    const float* xp = x + (r0 + l15) * 128 + k * 32 + q * 8;
    f32x4 xa = *(const f32x4*)xp;
    f32x4 xb = *(const f32x4*)(xp + 4);
    short8 af;
#pragma unroll
    for (int e = 0; e < 4; e++) { af[e] = (short)f2bf(xa[e]); af[4 + e] = (short)f2bf(xb[e]); }
#pragma unroll
    for (int dg = 0; dg < 8; dg++) {
      short8 bf = *(const short8*)(Wb1 + (dg * 16 + l15) * 128 + k * 32 + q * 8);
      acc[dg] = __builtin_amdgcn_mfma_f32_16x16x32_bf16(af, bf, acc[dg], 0, 0, 0);
    }
  }
#pragma unroll
  for (int dg = 0; dg < 8; dg++) {
    float bias = Wbias[dg * 16 + l15];
#pragma unroll
    for (int r = 0; r < 4; r++)
      hsm[w][q * 4 + r][dg * 16 + l15] = f2bf(acc[dg][r] + bias);
  }
  __syncthreads();
  // GEMM2: hA = h @ A  (B[k=d][col=e] = A[d][e] = Abt[e][d], contiguous in d)
  f32x4 acc2[8];
#pragma unroll
  for (int dg = 0; dg < 8; dg++) acc2[dg] = (f32x4){0.f, 0.f, 0.f, 0.f};
#pragma unroll
  for (int k = 0; k < 4; k++) {
    short8 af = *(short8*)&hsm[w][l15][k * 32 + q * 8];
#pragma unroll
    for (int dg = 0; dg < 8; dg++) {
      short8 bf = *(const short8*)(Abt + (dg * 16 + l15) * 128 + k * 32 + q * 8);
      acc2[dg] = __builtin_amdgcn_mfma_f32_16x16x32_bf16(af, bf, acc2[dg], 0, 0, 0);
    }
  }
#pragma unroll
  for (int dg = 0; dg < 8; dg++)
#pragma unroll
    for (int r = 0; r < 4; r++)
      hasm[w][q * 4 + r][dg * 16 + l15] = f2bf(acc2[dg][r]);
  __syncthreads();
  // store cat: cols 0..127 = hA, cols 128..255 = h
#pragma unroll
  for (int it = 0; it < 8; it++) {
    int idx = it * 64 + lane;
    int row = idx >> 5, c = idx & 31;
    short8 v = (c < 16) ? *(short8*)&hasm[w][row][c * 8]
                        : *(short8*)&hsm[w][row][(c - 16) * 8];
    *(short8*)(cat + ((r0 + row) << 8) + c * 8) = v;
  }
}

// ---------- k2: E once; s[k] += mask*exp(E); P_un packed-pair bf16 ----------
// grid (16, 4, B); 4 waves; wave w owns k-cols [kbase+w*32, +32), lane pair
// cols kc+2*l15, kc+2*l15+1. Block sweeps 16 j-tiles of 32 rows; counted
// vmcnt dbuf pipeline; ALL loop VMEM is GLL or stores (no VGPR loads).
__global__ __launch_bounds__(256, 2) void k2(const unsigned short* __restrict__ cat,
                                             const float* __restrict__ adj,
                                             unsigned short* __restrict__ pun,
                                             float* __restrict__ s_out) {
  __shared__ unsigned short cj[2][32 * 256];  // 2 x 16 KB cat tile, swizzled
  __shared__ float aj[2][32 * 128];           // 2 x 16 KB adj tile, swizzled
  const int t = threadIdx.x, w = t >> 6, lane = t & 63;
  const int q = lane >> 4, l15 = lane & 15;
  const int b = blockIdx.z;
  const int kbase = blockIdx.x * 128;
  const int j0b = blockIdx.y * 512;           // 16 tiles of 32 rows
  const size_t bN = (size_t)b * N_;
  const unsigned short* catp = cat + (bN << 8);
  const int kc = kbase + w * 32;
  short8 brg[2][8];  // catsw_k fragments for cols kc+2*l15+p (swap +16 mod 32)
#pragma unroll
  for (int p = 0; p < 2; p++) {
    int krow = kc + 2 * l15 + p;
#pragma unroll
    for (int m = 0; m < 8; m++)
      brg[p][m] = *(const short8*)(catp + (((size_t)krow) << 8) +
                                   ((((m * 4 + q) + 16) & 31) * 8));
  }
  float acc0 = 0.f, acc1 = 0.f;

  // stage: 4 GLL cat + 4 GLL adj per thread (8 per wave, wave-wide)
#define K2_STAGE(tt, bufi) do { \
    const int j0_ = j0b + (tt) * 32; \
    _Pragma("unroll") \
    for (int it = 0; it < 4; it++) { \
      int sI = it * 256 + t; \
      int row = sI >> 5, c = sI & 31; \
      GLL(catp + (((size_t)(j0_ + row)) << 8) + (c ^ (row & 7)) * 8, \
          (char*)cj[bufi] + sI * 16); \
    } \
    _Pragma("unroll") \
    for (int it = 0; it < 4; it++) { \
      int sI = it * 256 + t; \
      int row = sI >> 5, c = sI & 31; \
      GLL(adj + (((size_t)(bN + j0_ + row)) << 11) + kbase + ((c ^ (row & 7)) << 2), \
          (char*)aj[bufi] + sI * 16); \
    } } while (0)

#define K2_COMPUTE(tt, bufi) do { \
    const int j0_ = j0b + (tt) * 32; \
    _Pragma("unroll") \
    for (int jsub = 0; jsub < 2; jsub++) { \
      const int row = jsub * 16 + l15; \
      short8 afr[8]; \
      _Pragma("unroll") \
      for (int m = 0; m < 8; m++) \
        afr[m] = *(short8*)(cj[bufi] + row * 256 + (((m * 4 + q) ^ (l15 & 7)) * 8)); \
      f32x4 e0 = {0.f, 0.f, 0.f, 0.f}, e1 = {0.f, 0.f, 0.f, 0.f}; \
      _Pragma("unroll") \
      for (int m = 0; m < 8; m++) { \
        e0 = __builtin_amdgcn_mfma_f32_16x16x32_bf16(afr[m], brg[0][m], e0, 0, 0, 0); \
        e1 = __builtin_amdgcn_mfma_f32_16x16x32_bf16(afr[m], brg[1][m], e1, 0, 0, 0); \
      } \
      _Pragma("unroll") \
      for (int r = 0; r < 4; r++) { \
        int jr = jsub * 16 + q * 4 + r; \
        int jrow = j0_ + jr; \
        f32x2 av = *(const f32x2*)((const char*)aj[bufi] + jr * 512 + \
                    (((w * 8 + (l15 >> 1)) ^ (jr & 7)) << 4) + ((l15 & 1) << 3)); \
        float x0 = (av[0] > 0.f) ? __expf(fminf(e0[r], 60.f)) : 0.f; \
        float x1 = (av[1] > 0.f) ? __expf(fminf(e1[r], 60.f)) : 0.f; \
        acc0 += x0; acc1 += x1; \
        unsigned int pk = (unsigned int)f2bf(x0) | ((unsigned int)f2bf(x1) << 16); \
        *(unsigned int*)(pun + ((bN + jrow) << 11) + kc + 2 * l15) = pk; \
      } \
    } } while (0)

  K2_STAGE(0, 0);
  // tp = 0 peeled: only S(0)[8]+S(1)[8] outstanding -> retire S(0) = VMW(8)
  K2_STAGE(1, 1);
  VMW(8);
  BARRIER();
  K2_COMPUTE(0, 0);
  BARRIER();
#pragma unroll
  for (int tp = 1; tp < 15; tp++) {
    K2_STAGE(tp + 1, (tp + 1) & 1);
    VMW(16);          // retire S(tp); st(tp-1)[8] + S(tp+1)[8] stay in flight
    BARRIER();
    K2_COMPUTE(tp, tp & 1);
    BARRIER();
  }
  VMW(8);             // retire S(15); st(14)[8] in flight
  BARRIER();
  K2_COMPUTE(15, 1);
#undef K2_STAGE
#undef K2_COMPUTE

  acc0 += __shfl_xor(acc0, 16, 64); acc0 += __shfl_xor(acc0, 32, 64);
  acc1 += __shfl_xor(acc1, 16, 64); acc1 += __shfl_xor(acc1, 32, 64);
  if (lane < 16) {
    atomicAdd(&s_out[bN + kc + 2 * lane], acc0);
    atomicAdd(&s_out[bN + kc + 2 * lane + 1], acc1);
  }
}

// ---------- k1v: vt[b][d][j] = bf16(h[b][j][d] / s[j]) (R4-proven) ----------
__global__ __launch_bounds__(256) void k1v(const unsigned short* __restrict__ cat,
                                           const float* __restrict__ s,
                                           unsigned short* __restrict__ vt) {
  __shared__ unsigned short tile[64][136];
  __shared__ float rsv[64];
  const int t = threadIdx.x;
  const int b = blockIdx.y;
  const int nbase = blockIdx.x * 64;
  if (t < 64) rsv[t] = 1.f / s[(size_t)b * N_ + nbase + t];
#pragma unroll
  for (int k = 0; k < 4; k++) {
    int sI = t + 256 * k;
    int row = sI >> 4, part = sI & 15;
    *(short8*)&tile[row][part * 8] =
        *(const short8*)(cat + (((size_t)(b * N_ + nbase + row)) << 8) + 128 + part * 8);
  }
  __syncthreads();
#pragma unroll
  for (int k = 0; k < 4; k++) {
    int sI = t + 256 * k;
    int dd = sI >> 3, part = sI & 7;
    unsigned short tmp[8];
#pragma unroll
    for (int j = 0; j < 8; j++) {
      int jj = part * 8 + j;
      tmp[j] = f2bf(bf2f(tile[jj][dd]) * rsv[jj]);
    }
    *(short8*)(vt + (((size_t)(b * 128 + dd)) << 11) + nbase + part * 8) = *(short8*)tmp;
  }
}

// ---------- k3: h' = P_un @ V'; out = c*x + (1-c)*relu(h') ----------
// grid (N/32, B); 4 waves; wave w owns d-group [w*32, w*32+32); j-tile 128.
// 2x40KB dbuf, counted vmcnt(10) barriers (R14-proven).
__global__ __launch_bounds__(256) void k3(const unsigned short* __restrict__ pun,
                                          const unsigned short* __restrict__ vt,
                                          const float* __restrict__ x,
                                          const float* __restrict__ gw,
                                          const float* __restrict__ gb,
                                          float* __restrict__ out) {
  __shared__ char smem[2][40960];
  // per buffer: [0,8192): A-tile P_un 32 x 128j  [8192,40960): B-tile vt 128d x 128j
  const int t = threadIdx.x, w = t >> 6, lane = t & 63;
  const int q = lane >> 4, l15 = lane & 15;
  const int b = blockIdx.y, i0 = blockIdx.x * 32;
  const size_t bN = (size_t)b * N_;

  f32x4 acc[2][2];
#pragma unroll
  for (int ih = 0; ih < 2; ih++)
#pragma unroll
    for (int dh = 0; dh < 2; dh++) acc[ih][dh] = (f32x4){0.f, 0.f, 0.f, 0.f};

#define K3_STAGE(jtv, bufi) do { \
    const int j0_ = (jtv) * 128; \
    _Pragma("unroll") \
    for (int it = 0; it < 10; it++) { \
      int sI = it * 256 + t; \
      const unsigned short* g; \
      if (sI < 512) { \
        int row = sI >> 4, c = sI & 15; \
        g = pun + (((size_t)(bN + i0 + row)) << 11) + j0_ + ((c ^ (row & 7)) * 8); \
      } else { \
        int s2 = sI - 512; \
        int dd = s2 >> 4, c = s2 & 15; \
        g = vt + (((size_t)(b * 128 + dd)) << 11) + j0_ + ((c ^ (dd & 7)) * 8); \
      } \
      GLL(g, smem[bufi] + sI * 16); \
    } } while (0)

#define K3_COMPUTE(bufi) do { \
    unsigned short* pa = (unsigned short*)smem[bufi]; \
    unsigned short* vb = (unsigned short*)(smem[bufi] + 8192); \
    _Pragma("unroll") \
    for (int ks = 0; ks < 4; ks++) { \
      short8 af[2], bf[2]; \
      _Pragma("unroll") \
      for (int ih = 0; ih < 2; ih++) { \
        int m = ih * 16 + l15; \
        af[ih] = *(short8*)(pa + m * 128 + (((ks * 4 + q) ^ (m & 7)) * 8)); \
      } \
      _Pragma("unroll") \
      for (int dh = 0; dh < 2; dh++) { \
        int d = w * 32 + dh * 16 + l15; \
        bf[dh] = *(short8*)(vb + d * 128 + (((ks * 4 + q) ^ (d & 7)) * 8)); \
      } \
      acc[0][0] = __builtin_amdgcn_mfma_f32_16x16x32_bf16(af[0], bf[0], acc[0][0], 0, 0, 0); \
      acc[0][1] = __builtin_amdgcn_mfma_f32_16x16x32_bf16(af[0], bf[1], acc[0][1], 0, 0, 0); \
      acc[1][0] = __builtin_amdgcn_mfma_f32_16x16x32_bf16(af[1], bf[0], acc[1][0], 0, 0, 0); \
      acc[1][1] = __builtin_amdgcn_mfma_f32_16x16x32_bf16(af[1], bf[1], acc[1][1], 0, 0, 0); \
    } } while (0)

  K3_STAGE(0, 0);
  for (int jt = 0; jt < 15; jt++) {
    K3_STAGE(jt + 1, (jt + 1) & 1);
    asm volatile("s_waitcnt vmcnt(10)" ::: "memory");
    BARRIER();
    K3_COMPUTE(jt & 1);
    BARRIER();
  }
  asm volatile("s_waitcnt vmcnt(0)" ::: "memory");
  BARRIER();
  K3_COMPUTE(1);   // jt = 15
  __syncthreads(); // all reads done before epilogue reuses smem[0]
#undef K3_STAGE
#undef K3_COMPUTE

  // epilogue: relu -> LDS f32, gate, sigmoid, blend, store
  float* hs = (float*)smem[0];            // 32 x 132 f32 = 16896 B
  float* co = (float*)(smem[0] + 16896);  // 32 f32
#pragma unroll
  for (int ih = 0; ih < 2; ih++)
#pragma unroll
    for (int dh = 0; dh < 2; dh++)
#pragma unroll
      for (int r = 0; r < 4; r++) {
        int row = ih * 16 + q * 4 + r;
        int d = w * 32 + dh * 16 + l15;
        hs[row * 132 + d] = fmaxf(acc[ih][dh][r], 0.f);
      }
  __syncthreads();
  {
    int grow = t >> 3, sub = t & 7;
    const float* xr = x + (((size_t)(bN + i0 + grow)) << 7);
    float z = 0.f;
#pragma unroll
    for (int k = 0; k < 16; k++) {
      int dd = sub + 8 * k;
      z += gw[dd] * xr[dd] + gw[128 + dd] * hs[grow * 132 + dd];
    }
    z += __shfl_xor(z, 1, 64);
    z += __shfl_xor(z, 2, 64);
    z += __shfl_xor(z, 4, 64);
    if (sub == 0) co[grow] = 1.f / (1.f + __expf(-(z + gb[0])));
  }
  __syncthreads();
#pragma unroll
  for (int kk = 0; kk < 4; kk++) {
    int id = kk * 256 + t;
    int row = id >> 5, c4 = id & 31;
    size_t g = (((size_t)(bN + i0 + row)) << 7) + c4 * 4;
    f32x4 xv = *(const f32x4*)(x + g);
    f32x4 hv = *(const f32x4*)(hs + row * 132 + c4 * 4);
    float cf = co[row];
    f32x4 o;
#pragma unroll
    for (int e = 0; e < 4; e++) o[e] = cf * xv[e] + (1.f - cf) * hv[e];
    *(f32x4*)(out + g) = o;
  }
}

extern "C" void kernel_launch(void* const* d_in, const int* in_sizes, int n_in,
                              void* d_out, int out_size, void* d_ws, size_t ws_size,
                              hipStream_t stream) {
  const float* x   = (const float*)d_in[0];
  const float* adj = (const float*)d_in[1];
  const float* Ww  = (const float*)d_in[2];
  const float* Wb  = (const float*)d_in[3];
  const float* A   = (const float*)d_in[4];
  const float* gw  = (const float*)d_in[5];
  const float* gb  = (const float*)d_in[6];
  float* out = (float*)d_out;
  char* ws = (char*)d_ws;

  unsigned short* cat = (unsigned short*)(ws + CAT_OFF);
  unsigned short* vt  = (unsigned short*)(ws + VT_OFF);
  unsigned short* pun = (unsigned short*)(ws + PUN_OFF);
  float* s  = (float*)(ws + S_OFF);
  unsigned short* Wb1 = (unsigned short*)(ws + WB_OFF);
  unsigned short* Abt = (unsigned short*)(ws + AT_OFF);

  hipMemsetAsync(s, 0, (size_t)B_ * N_ * sizeof(float), stream);
  k_cvt<<<64, 256, 0, stream>>>(Ww, A, Wb1, Abt);
  k1<<<(B_ * N_) / 64, 256, 0, stream>>>(x, Wb1, Wb, Abt, cat);
  k2<<<dim3(16, 4, B_), 256, 0, stream>>>(cat, adj, pun, s);
  k1v<<<dim3(N_ / 64, B_), 256, 0, stream>>>(cat, s, vt);
  k3<<<dim3(N_ / 32, B_), 256, 0, stream>>>(pun, vt, x, gw, gb, out);
}

// Round 7
// 263.488 us; speedup vs baseline: 1.0106x; 1.0009x over previous
//
#include <hip/hip_runtime.h>

// GAT_gate: B=8, N=2048, D=128
// out = c*x + (1-c)*relu(att@h), att = colsoftmax(mask(hA h^T + h hA^T))*adj
// e small (|e|<~6) -> exp without max-subtraction (clamp 60).
// cat[n][0:128]=hA[n], cat[n][128:256]=h[n]; e[i,j] = cat[i] . catsw[j].
// R16 = best-known composition, no experiments:
//  - k2: VERBATIM R11 (measured 82.0us: stage cat+adj via GLL, __syncthreads
//    drain, 64KB LDS, grid (16,16,8)). R13-R15 post-mortems: every pipelined
//    k2 variant (counted vmcnt / raw barriers) landed 120-128us; both
//    non-pipelined variants 78-82us. Stop pipelining k2.
//  - k3: VERBATIM R14 (counted vmcnt(10), 2x40KB dbuf; proven ~40us by
//    R14 decomposition: total flat while k2 +50 => k3 -35).
//  - k1/k1v/k_cvt unchanged.

#define B_ 8
#define N_ 2048
#define D_ 128

typedef __attribute__((ext_vector_type(8))) short short8;
typedef __attribute__((ext_vector_type(4))) float f32x4;
typedef __attribute__((ext_vector_type(2))) float f32x2;

#define GLL(gp, lp) __builtin_amdgcn_global_load_lds( \
    (__attribute__((address_space(1))) const unsigned int*)(gp), \
    (__attribute__((address_space(3))) unsigned int*)(lp), 16, 0, 0)

#define BARRIER() __builtin_amdgcn_s_barrier()

static __device__ __forceinline__ unsigned short f2bf(float f) {
  union { float f; unsigned int u; } v; v.f = f;
  unsigned int r = v.u + 0x7fffu + ((v.u >> 16) & 1u);
  return (unsigned short)(r >> 16);
}
static __device__ __forceinline__ float bf2f(unsigned short u) {
  union { unsigned int u; float f; } v; v.u = ((unsigned int)u) << 16;
  return v.f;
}

// ---- workspace layout (bytes) ----
#define CAT_OFF  ((size_t)0)         // bf16 cat [B][N][256]        8 MB
#define VT_OFF   ((size_t)8388608)   // bf16 V'^T [B][128][N]       4 MB
#define PUN_OFF  ((size_t)12582912)  // bf16 P_un [B][N][N]         67.1 MB
#define S_OFF    ((size_t)79691776)  // f32 colsum s [B][N]         64 KB
#define WB_OFF   ((size_t)79757312)  // bf16 W [128][128]           32 KB
#define AT_OFF   ((size_t)79790080)  // bf16 A^T [128][128]         32 KB

// ---------- prep: W -> bf16 (same layout), A -> bf16 transposed ----------
__global__ __launch_bounds__(256) void k_cvt(const float* __restrict__ W,
                                             const float* __restrict__ A,
                                             unsigned short* __restrict__ Wb1,
                                             unsigned short* __restrict__ Abt) {
  int i = blockIdx.x * 256 + threadIdx.x;   // grid 64 blocks covers 128*128
  Wb1[i] = f2bf(W[i]);
  Abt[(i & 127) * 128 + (i >> 7)] = f2bf(A[i]);
}

// ---------- k1: h = x@W^T + b, hA = h@A via MFMA; write cat bf16 ----------
// grid 256 blocks; 4 waves; wave w owns rows blockIdx.x*64 + w*16 .. +16.
__global__ __launch_bounds__(256) void k1(const float* __restrict__ x,
                                          const unsigned short* __restrict__ Wb1,
                                          const float* __restrict__ Wbias,
                                          const unsigned short* __restrict__ Abt,
                                          unsigned short* __restrict__ cat) {
  __shared__ unsigned short hsm[4][16][136];   // 272 B rows, 16B-aligned
  __shared__ unsigned short hasm[4][16][136];
  const int t = threadIdx.x, w = t >> 6, lane = t & 63;
  const int q = lane >> 4, l15 = lane & 15;
  const size_t r0 = (size_t)blockIdx.x * 64 + w * 16;

  f32x4 acc[8];
#pragma unroll
  for (int dg = 0; dg < 8; dg++) acc[dg] = (f32x4){0.f, 0.f, 0.f, 0.f};
  // GEMM1: h = x @ W^T  (B[k=f][col=d] = W[d][f], contiguous in f)
#pragma unroll
  for (int k = 0; k < 4; k++) {
    const float* xp = x + (r0 + l15) * 128 + k * 32 + q * 8;
    f32x4 xa = *(const f32x4*)xp;
    f32x4 xb = *(const f32x4*)(xp + 4);
    short8 af;
#pragma unroll
    for (int e = 0; e < 4; e++) { af[e] = (short)f2bf(xa[e]); af[4 + e] = (short)f2bf(xb[e]); }
#pragma unroll
    for (int dg = 0; dg < 8; dg++) {
      short8 bf = *(const short8*)(Wb1 + (dg * 16 + l15) * 128 + k * 32 + q * 8);
      acc[dg] = __builtin_amdgcn_mfma_f32_16x16x32_bf16(af, bf, acc[dg], 0, 0, 0);
    }
  }
#pragma unroll
  for (int dg = 0; dg < 8; dg++) {
    float bias = Wbias[dg * 16 + l15];
#pragma unroll
    for (int r = 0; r < 4; r++)
      hsm[w][q * 4 + r][dg * 16 + l15] = f2bf(acc[dg][r] + bias);
  }
  __syncthreads();
  // GEMM2: hA = h @ A  (B[k=d][col=e] = A[d][e] = Abt[e][d], contiguous in d)
  f32x4 acc2[8];
#pragma unroll
  for (int dg = 0; dg < 8; dg++) acc2[dg] = (f32x4){0.f, 0.f, 0.f, 0.f};
#pragma unroll
  for (int k = 0; k < 4; k++) {
    short8 af = *(short8*)&hsm[w][l15][k * 32 + q * 8];
#pragma unroll
    for (int dg = 0; dg < 8; dg++) {
      short8 bf = *(const short8*)(Abt + (dg * 16 + l15) * 128 + k * 32 + q * 8);
      acc2[dg] = __builtin_amdgcn_mfma_f32_16x16x32_bf16(af, bf, acc2[dg], 0, 0, 0);
    }
  }
#pragma unroll
  for (int dg = 0; dg < 8; dg++)
#pragma unroll
    for (int r = 0; r < 4; r++)
      hasm[w][q * 4 + r][dg * 16 + l15] = f2bf(acc2[dg][r]);
  __syncthreads();
  // store cat: cols 0..127 = hA, cols 128..255 = h
#pragma unroll
  for (int it = 0; it < 8; it++) {
    int idx = it * 64 + lane;
    int row = idx >> 5, c = idx & 31;
    short8 v = (c < 16) ? *(short8*)&hasm[w][row][c * 8]
                        : *(short8*)&hsm[w][row][(c - 16) * 8];
    *(short8*)(cat + ((r0 + row) << 8) + c * 8) = v;
  }
}

// ---------- k2: E once; s[k] += mask*exp(E); P_un packed-pair bf16 ----------
// grid (N/128, 16, B); 4 waves; wave w owns k-cols [kbase+w*32, +32),
// lane pair cols kc+2*l15, kc+2*l15+1. LDS-staged cat tile + adj tile
// (both via global_load_lds, drained at the same barrier). R11-proven 82us.
__global__ __launch_bounds__(256, 2) void k2(const unsigned short* __restrict__ cat,
                                             const float* __restrict__ adj,
                                             unsigned short* __restrict__ pun,
                                             float* __restrict__ s_out) {
  __shared__ unsigned short cj[64 * 256];  // 32 KB, XOR-swizzled chunks
  __shared__ float aj[64 * 128];           // 32 KB adj tile, XOR-swizzled chunks
  const int t = threadIdx.x, w = t >> 6, lane = t & 63;
  const int q = lane >> 4, l15 = lane & 15;
  const int b = blockIdx.z;
  const int kbase = blockIdx.x * 128;
  const int j0b = blockIdx.y * 128;
  const size_t bN = (size_t)b * N_;
  const unsigned short* catp = cat + (bN << 8);
  const int kc = kbase + w * 32;
  short8 brg[2][8];  // catsw_k fragments for cols kc+2*l15+p (swap +16 mod 32)
#pragma unroll
  for (int p = 0; p < 2; p++) {
    int krow = kc + 2 * l15 + p;
#pragma unroll
    for (int m = 0; m < 8; m++)
      brg[p][m] = *(const short8*)(catp + (((size_t)krow) << 8) +
                                   ((((m * 4 + q) + 16) & 31) * 8));
  }
  float acc0 = 0.f, acc1 = 0.f;
  for (int jt = 0; jt < 2; jt++) {
    const int j0 = j0b + jt * 64;
    // stage cat tile (32KB) + adj tile (32KB); both drain at the barrier.
#pragma unroll
    for (int it = 0; it < 8; it++) {
      int sI = it * 256 + t;
      int row = sI >> 5, c = sI & 31;
      GLL(catp + (((size_t)(j0 + row)) << 8) + (c ^ (row & 7)) * 8,
          (char*)cj + sI * 16);
    }
#pragma unroll
    for (int it = 0; it < 8; it++) {
      int sI = it * 256 + t;
      int row = sI >> 5, c = sI & 31;   // adj row: 128 f32 = 32 x 16B chunks
      GLL(adj + (((size_t)(bN + j0 + row)) << 11) + kbase + ((c ^ (row & 7)) << 2),
          (char*)aj + sI * 16);
    }
    __syncthreads();
#pragma unroll
    for (int jsub = 0; jsub < 4; jsub++) {
      const int row = jsub * 16 + l15;
      short8 afr[8];
#pragma unroll
      for (int m = 0; m < 8; m++)
        afr[m] = *(short8*)(cj + row * 256 + (((m * 4 + q) ^ (l15 & 7)) * 8));
      f32x4 e0 = {0.f, 0.f, 0.f, 0.f}, e1 = {0.f, 0.f, 0.f, 0.f};
#pragma unroll
      for (int m = 0; m < 8; m++) {
        e0 = __builtin_amdgcn_mfma_f32_16x16x32_bf16(afr[m], brg[0][m], e0, 0, 0, 0);
        e1 = __builtin_amdgcn_mfma_f32_16x16x32_bf16(afr[m], brg[1][m], e1, 0, 0, 0);
      }
#pragma unroll
      for (int r = 0; r < 4; r++) {
        int jr = jsub * 16 + q * 4 + r;       // local row in 64-row tile
        int jrow = j0 + jr;                   // global row
        // swizzled LDS read of adj pair (cols kc+2*l15, +1)
        f32x2 av = *(const f32x2*)((const char*)aj + jr * 512 +
                    (((w * 8 + (l15 >> 1)) ^ (jr & 7)) << 4) + ((l15 & 1) << 3));
        float x0 = (av[0] > 0.f) ? __expf(fminf(e0[r], 60.f)) : 0.f;
        float x1 = (av[1] > 0.f) ? __expf(fminf(e1[r], 60.f)) : 0.f;
        acc0 += x0; acc1 += x1;
        unsigned int pk = (unsigned int)f2bf(x0) | ((unsigned int)f2bf(x1) << 16);
        *(unsigned int*)(pun + ((bN + jrow) << 11) + kc + 2 * l15) = pk;
      }
    }
    __syncthreads();
  }
  acc0 += __shfl_xor(acc0, 16, 64); acc0 += __shfl_xor(acc0, 32, 64);
  acc1 += __shfl_xor(acc1, 16, 64); acc1 += __shfl_xor(acc1, 32, 64);
  if (lane < 16) {
    atomicAdd(&s_out[bN + kc + 2 * lane], acc0);
    atomicAdd(&s_out[bN + kc + 2 * lane + 1], acc1);
  }
}

// ---------- k1v: vt[b][d][j] = bf16(h[b][j][d] / s[j]) (R4-proven) ----------
__global__ __launch_bounds__(256) void k1v(const unsigned short* __restrict__ cat,
                                           const float* __restrict__ s,
                                           unsigned short* __restrict__ vt) {
  __shared__ unsigned short tile[64][136];
  __shared__ float rsv[64];
  const int t = threadIdx.x;
  const int b = blockIdx.y;
  const int nbase = blockIdx.x * 64;
  if (t < 64) rsv[t] = 1.f / s[(size_t)b * N_ + nbase + t];
#pragma unroll
  for (int k = 0; k < 4; k++) {
    int sI = t + 256 * k;
    int row = sI >> 4, part = sI & 15;
    *(short8*)&tile[row][part * 8] =
        *(const short8*)(cat + (((size_t)(b * N_ + nbase + row)) << 8) + 128 + part * 8);
  }
  __syncthreads();
#pragma unroll
  for (int k = 0; k < 4; k++) {
    int sI = t + 256 * k;
    int dd = sI >> 3, part = sI & 7;
    unsigned short tmp[8];
#pragma unroll
    for (int j = 0; j < 8; j++) {
      int jj = part * 8 + j;
      tmp[j] = f2bf(bf2f(tile[jj][dd]) * rsv[jj]);
    }
    *(short8*)(vt + (((size_t)(b * 128 + dd)) << 11) + nbase + part * 8) = *(short8*)tmp;
  }
}

// ---------- k3: h' = P_un @ V'; out = c*x + (1-c)*relu(h') ----------
// grid (N/32, B); 4 waves; wave w owns d-group [w*32, w*32+32); j-tile 128.
// 2x40KB dbuf, counted vmcnt(10) barriers (R14-proven).
__global__ __launch_bounds__(256) void k3(const unsigned short* __restrict__ pun,
                                          const unsigned short* __restrict__ vt,
                                          const float* __restrict__ x,
                                          const float* __restrict__ gw,
                                          const float* __restrict__ gb,
                                          float* __restrict__ out) {
  __shared__ char smem[2][40960];
  // per buffer: [0,8192): A-tile P_un 32 x 128j  [8192,40960): B-tile vt 128d x 128j
  const int t = threadIdx.x, w = t >> 6, lane = t & 63;
  const int q = lane >> 4, l15 = lane & 15;
  const int b = blockIdx.y, i0 = blockIdx.x * 32;
  const size_t bN = (size_t)b * N_;

  f32x4 acc[2][2];
#pragma unroll
  for (int ih = 0; ih < 2; ih++)
#pragma unroll
    for (int dh = 0; dh < 2; dh++) acc[ih][dh] = (f32x4){0.f, 0.f, 0.f, 0.f};

#define K3_STAGE(jtv, bufi) do { \
    const int j0_ = (jtv) * 128; \
    _Pragma("unroll") \
    for (int it = 0; it < 10; it++) { \
      int sI = it * 256 + t; \
      const unsigned short* g; \
      if (sI < 512) { \
        int row = sI >> 4, c = sI & 15; \
        g = pun + (((size_t)(bN + i0 + row)) << 11) + j0_ + ((c ^ (row & 7)) * 8); \
      } else { \
        int s2 = sI - 512; \
        int dd = s2 >> 4, c = s2 & 15; \
        g = vt + (((size_t)(b * 128 + dd)) << 11) + j0_ + ((c ^ (dd & 7)) * 8); \
      } \
      GLL(g, smem[bufi] + sI * 16); \
    } } while (0)

#define K3_COMPUTE(bufi) do { \
    unsigned short* pa = (unsigned short*)smem[bufi]; \
    unsigned short* vb = (unsigned short*)(smem[bufi] + 8192); \
    _Pragma("unroll") \
    for (int ks = 0; ks < 4; ks++) { \
      short8 af[2], bf[2]; \
      _Pragma("unroll") \
      for (int ih = 0; ih < 2; ih++) { \
        int m = ih * 16 + l15; \
        af[ih] = *(short8*)(pa + m * 128 + (((ks * 4 + q) ^ (m & 7)) * 8)); \
      } \
      _Pragma("unroll") \
      for (int dh = 0; dh < 2; dh++) { \
        int d = w * 32 + dh * 16 + l15; \
        bf[dh] = *(short8*)(vb + d * 128 + (((ks * 4 + q) ^ (d & 7)) * 8)); \
      } \
      acc[0][0] = __builtin_amdgcn_mfma_f32_16x16x32_bf16(af[0], bf[0], acc[0][0], 0, 0, 0); \
      acc[0][1] = __builtin_amdgcn_mfma_f32_16x16x32_bf16(af[0], bf[1], acc[0][1], 0, 0, 0); \
      acc[1][0] = __builtin_amdgcn_mfma_f32_16x16x32_bf16(af[1], bf[0], acc[1][0], 0, 0, 0); \
      acc[1][1] = __builtin_amdgcn_mfma_f32_16x16x32_bf16(af[1], bf[1], acc[1][1], 0, 0, 0); \
    } } while (0)

  K3_STAGE(0, 0);
  for (int jt = 0; jt < 15; jt++) {
    K3_STAGE(jt + 1, (jt + 1) & 1);
    asm volatile("s_waitcnt vmcnt(10)" ::: "memory");
    BARRIER();
    K3_COMPUTE(jt & 1);
    BARRIER();
  }
  asm volatile("s_waitcnt vmcnt(0)" ::: "memory");
  BARRIER();
  K3_COMPUTE(1);   // jt = 15
  __syncthreads(); // all reads done before epilogue reuses smem[0]
#undef K3_STAGE
#undef K3_COMPUTE

  // epilogue: relu -> LDS f32, gate, sigmoid, blend, store
  float* hs = (float*)smem[0];            // 32 x 132 f32 = 16896 B
  float* co = (float*)(smem[0] + 16896);  // 32 f32
#pragma unroll
  for (int ih = 0; ih < 2; ih++)
#pragma unroll
    for (int dh = 0; dh < 2; dh++)
#pragma unroll
      for (int r = 0; r < 4; r++) {
        int row = ih * 16 + q * 4 + r;
        int d = w * 32 + dh * 16 + l15;
        hs[row * 132 + d] = fmaxf(acc[ih][dh][r], 0.f);
      }
  __syncthreads();
  {
    int grow = t >> 3, sub = t & 7;
    const float* xr = x + (((size_t)(bN + i0 + grow)) << 7);
    float z = 0.f;
#pragma unroll
    for (int k = 0; k < 16; k++) {
      int dd = sub + 8 * k;
      z += gw[dd] * xr[dd] + gw[128 + dd] * hs[grow * 132 + dd];
    }
    z += __shfl_xor(z, 1, 64);
    z += __shfl_xor(z, 2, 64);
    z += __shfl_xor(z, 4, 64);
    if (sub == 0) co[grow] = 1.f / (1.f + __expf(-(z + gb[0])));
  }
  __syncthreads();
#pragma unroll
  for (int kk = 0; kk < 4; kk++) {
    int id = kk * 256 + t;
    int row = id >> 5, c4 = id & 31;
    size_t g = (((size_t)(bN + i0 + row)) << 7) + c4 * 4;
    f32x4 xv = *(const f32x4*)(x + g);
    f32x4 hv = *(const f32x4*)(hs + row * 132 + c4 * 4);
    float cf = co[row];
    f32x4 o;
#pragma unroll
    for (int e = 0; e < 4; e++) o[e] = cf * xv[e] + (1.f - cf) * hv[e];
    *(f32x4*)(out + g) = o;
  }
}

extern "C" void kernel_launch(void* const* d_in, const int* in_sizes, int n_in,
                              void* d_out, int out_size, void* d_ws, size_t ws_size,
                              hipStream_t stream) {
  const float* x   = (const float*)d_in[0];
  const float* adj = (const float*)d_in[1];
  const float* Ww  = (const float*)d_in[2];
  const float* Wb  = (const float*)d_in[3];
  const float* A   = (const float*)d_in[4];
  const float* gw  = (const float*)d_in[5];
  const float* gb  = (const float*)d_in[6];
  float* out = (float*)d_out;
  char* ws = (char*)d_ws;

  unsigned short* cat = (unsigned short*)(ws + CAT_OFF);
  unsigned short* vt  = (unsigned short*)(ws + VT_OFF);
  unsigned short* pun = (unsigned short*)(ws + PUN_OFF);
  float* s  = (float*)(ws + S_OFF);
  unsigned short* Wb1 = (unsigned short*)(ws + WB_OFF);
  unsigned short* Abt = (unsigned short*)(ws + AT_OFF);

  hipMemsetAsync(s, 0, (size_t)B_ * N_ * sizeof(float), stream);
  k_cvt<<<64, 256, 0, stream>>>(Ww, A, Wb1, Abt);
  k1<<<(B_ * N_) / 64, 256, 0, stream>>>(x, Wb1, Wb, Abt, cat);
  k2<<<dim3(N_ / 128, 16, B_), 256, 0, stream>>>(cat, adj, pun, s);
  k1v<<<dim3(N_ / 64, B_), 256, 0, stream>>>(cat, s, vt);
  k3<<<dim3(N_ / 32, B_), 256, 0, stream>>>(pun, vt, x, gw, gb, out);
}

// Round 8
// 259.582 us; speedup vs baseline: 1.0259x; 1.0150x over previous
//
#include <hip/hip_runtime.h>

// GAT_gate: B=8, N=2048, D=128
// out = c*x + (1-c)*relu(att@h), att = colsoftmax(mask(hA h^T + h hA^T))*adj
// e small (|e|<~6) -> exp without max-subtraction (clamp 60).
// cat[n][0:128]=hA[n], cat[n][128:256]=h[n]; e[i,j] = cat[i] . catsw[j].
// R17: traffic-reduction round.
//  R11-R16 post-mortem: clean totals pinned 263.5-266.3 across 5 structurally
//  different k2/k3 variants; rocprof per-dispatch times (replay+flush) do not
//  reflect clean runs. Fitted model: k2~80, k3~84 clean in ALL variants; both
//  at ~4.2 TB/s aggregate (HBM+LLC) traffic -> traffic-bound, scheduling-
//  invariant. Only lever: move less data.
//  Change (k3 only, attribution-clean): i-tile 32->64. vt re-reads halve
//  (256->128 MB); total staged 328->197 MB. Geometry-scaled R14 counted-vmcnt
//  dbuf: j-tile 64, 2x24KB LDS, 6 GLL/thread/tile, steady vmcnt(6).
//  Same global j accumulation order -> bit-identical numerics.
//  k2 = R11 verbatim (~80us clean). k1/k1v/k_cvt unchanged.

#define B_ 8
#define N_ 2048
#define D_ 128

typedef __attribute__((ext_vector_type(8))) short short8;
typedef __attribute__((ext_vector_type(4))) float f32x4;
typedef __attribute__((ext_vector_type(2))) float f32x2;

#define GLL(gp, lp) __builtin_amdgcn_global_load_lds( \
    (__attribute__((address_space(1))) const unsigned int*)(gp), \
    (__attribute__((address_space(3))) unsigned int*)(lp), 16, 0, 0)

#define BARRIER() __builtin_amdgcn_s_barrier()

static __device__ __forceinline__ unsigned short f2bf(float f) {
  union { float f; unsigned int u; } v; v.f = f;
  unsigned int r = v.u + 0x7fffu + ((v.u >> 16) & 1u);
  return (unsigned short)(r >> 16);
}
static __device__ __forceinline__ float bf2f(unsigned short u) {
  union { unsigned int u; float f; } v; v.u = ((unsigned int)u) << 16;
  return v.f;
}

// ---- workspace layout (bytes) ----
#define CAT_OFF  ((size_t)0)         // bf16 cat [B][N][256]        8 MB
#define VT_OFF   ((size_t)8388608)   // bf16 V'^T [B][128][N]       4 MB
#define PUN_OFF  ((size_t)12582912)  // bf16 P_un [B][N][N]         67.1 MB
#define S_OFF    ((size_t)79691776)  // f32 colsum s [B][N]         64 KB
#define WB_OFF   ((size_t)79757312)  // bf16 W [128][128]           32 KB
#define AT_OFF   ((size_t)79790080)  // bf16 A^T [128][128]         32 KB

// ---------- prep: W -> bf16 (same layout), A -> bf16 transposed ----------
__global__ __launch_bounds__(256) void k_cvt(const float* __restrict__ W,
                                             const float* __restrict__ A,
                                             unsigned short* __restrict__ Wb1,
                                             unsigned short* __restrict__ Abt) {
  int i = blockIdx.x * 256 + threadIdx.x;   // grid 64 blocks covers 128*128
  Wb1[i] = f2bf(W[i]);
  Abt[(i & 127) * 128 + (i >> 7)] = f2bf(A[i]);
}

// ---------- k1: h = x@W^T + b, hA = h@A via MFMA; write cat bf16 ----------
// grid 256 blocks; 4 waves; wave w owns rows blockIdx.x*64 + w*16 .. +16.
__global__ __launch_bounds__(256) void k1(const float* __restrict__ x,
                                          const unsigned short* __restrict__ Wb1,
                                          const float* __restrict__ Wbias,
                                          const unsigned short* __restrict__ Abt,
                                          unsigned short* __restrict__ cat) {
  __shared__ unsigned short hsm[4][16][136];   // 272 B rows, 16B-aligned
  __shared__ unsigned short hasm[4][16][136];
  const int t = threadIdx.x, w = t >> 6, lane = t & 63;
  const int q = lane >> 4, l15 = lane & 15;
  const size_t r0 = (size_t)blockIdx.x * 64 + w * 16;

  f32x4 acc[8];
#pragma unroll
  for (int dg = 0; dg < 8; dg++) acc[dg] = (f32x4){0.f, 0.f, 0.f, 0.f};
  // GEMM1: h = x @ W^T  (B[k=f][col=d] = W[d][f], contiguous in f)
#pragma unroll
  for (int k = 0; k < 4; k++) {
    const float* xp = x + (r0 + l15) * 128 + k * 32 + q * 8;
    f32x4 xa = *(const f32x4*)xp;
    f32x4 xb = *(const f32x4*)(xp + 4);
    short8 af;
#pragma unroll
    for (int e = 0; e < 4; e++) { af[e] = (short)f2bf(xa[e]); af[4 + e] = (short)f2bf(xb[e]); }
#pragma unroll
    for (int dg = 0; dg < 8; dg++) {
      short8 bf = *(const short8*)(Wb1 + (dg * 16 + l15) * 128 + k * 32 + q * 8);
      acc[dg] = __builtin_amdgcn_mfma_f32_16x16x32_bf16(af, bf, acc[dg], 0, 0, 0);
    }
  }
#pragma unroll
  for (int dg = 0; dg < 8; dg++) {
    float bias = Wbias[dg * 16 + l15];
#pragma unroll
    for (int r = 0; r < 4; r++)
      hsm[w][q * 4 + r][dg * 16 + l15] = f2bf(acc[dg][r] + bias);
  }
  __syncthreads();
  // GEMM2: hA = h @ A  (B[k=d][col=e] = A[d][e] = Abt[e][d], contiguous in d)
  f32x4 acc2[8];
#pragma unroll
  for (int dg = 0; dg < 8; dg++) acc2[dg] = (f32x4){0.f, 0.f, 0.f, 0.f};
#pragma unroll
  for (int k = 0; k < 4; k++) {
    short8 af = *(short8*)&hsm[w][l15][k * 32 + q * 8];
#pragma unroll
    for (int dg = 0; dg < 8; dg++) {
      short8 bf = *(const short8*)(Abt + (dg * 16 + l15) * 128 + k * 32 + q * 8);
      acc2[dg] = __builtin_amdgcn_mfma_f32_16x16x32_bf16(af, bf, acc2[dg], 0, 0, 0);
    }
  }
#pragma unroll
  for (int dg = 0; dg < 8; dg++)
#pragma unroll
    for (int r = 0; r < 4; r++)
      hasm[w][q * 4 + r][dg * 16 + l15] = f2bf(acc2[dg][r]);
  __syncthreads();
  // store cat: cols 0..127 = hA, cols 128..255 = h
#pragma unroll
  for (int it = 0; it < 8; it++) {
    int idx = it * 64 + lane;
    int row = idx >> 5, c = idx & 31;
    short8 v = (c < 16) ? *(short8*)&hasm[w][row][c * 8]
                        : *(short8*)&hsm[w][row][(c - 16) * 8];
    *(short8*)(cat + ((r0 + row) << 8) + c * 8) = v;
  }
}

// ---------- k2: E once; s[k] += mask*exp(E); P_un packed-pair bf16 ----------
// grid (N/128, 16, B); 4 waves; wave w owns k-cols [kbase+w*32, +32),
// lane pair cols kc+2*l15, kc+2*l15+1. LDS-staged cat tile + adj tile
// (both via global_load_lds, drained at the same barrier). R11-proven.
__global__ __launch_bounds__(256, 2) void k2(const unsigned short* __restrict__ cat,
                                             const float* __restrict__ adj,
                                             unsigned short* __restrict__ pun,
                                             float* __restrict__ s_out) {
  __shared__ unsigned short cj[64 * 256];  // 32 KB, XOR-swizzled chunks
  __shared__ float aj[64 * 128];           // 32 KB adj tile, XOR-swizzled chunks
  const int t = threadIdx.x, w = t >> 6, lane = t & 63;
  const int q = lane >> 4, l15 = lane & 15;
  const int b = blockIdx.z;
  const int kbase = blockIdx.x * 128;
  const int j0b = blockIdx.y * 128;
  const size_t bN = (size_t)b * N_;
  const unsigned short* catp = cat + (bN << 8);
  const int kc = kbase + w * 32;
  short8 brg[2][8];  // catsw_k fragments for cols kc+2*l15+p (swap +16 mod 32)
#pragma unroll
  for (int p = 0; p < 2; p++) {
    int krow = kc + 2 * l15 + p;
#pragma unroll
    for (int m = 0; m < 8; m++)
      brg[p][m] = *(const short8*)(catp + (((size_t)krow) << 8) +
                                   ((((m * 4 + q) + 16) & 31) * 8));
  }
  float acc0 = 0.f, acc1 = 0.f;
  for (int jt = 0; jt < 2; jt++) {
    const int j0 = j0b + jt * 64;
    // stage cat tile (32KB) + adj tile (32KB); both drain at the barrier.
#pragma unroll
    for (int it = 0; it < 8; it++) {
      int sI = it * 256 + t;
      int row = sI >> 5, c = sI & 31;
      GLL(catp + (((size_t)(j0 + row)) << 8) + (c ^ (row & 7)) * 8,
          (char*)cj + sI * 16);
    }
#pragma unroll
    for (int it = 0; it < 8; it++) {
      int sI = it * 256 + t;
      int row = sI >> 5, c = sI & 31;   // adj row: 128 f32 = 32 x 16B chunks
      GLL(adj + (((size_t)(bN + j0 + row)) << 11) + kbase + ((c ^ (row & 7)) << 2),
          (char*)aj + sI * 16);
    }
    __syncthreads();
#pragma unroll
    for (int jsub = 0; jsub < 4; jsub++) {
      const int row = jsub * 16 + l15;
      short8 afr[8];
#pragma unroll
      for (int m = 0; m < 8; m++)
        afr[m] = *(short8*)(cj + row * 256 + (((m * 4 + q) ^ (l15 & 7)) * 8));
      f32x4 e0 = {0.f, 0.f, 0.f, 0.f}, e1 = {0.f, 0.f, 0.f, 0.f};
#pragma unroll
      for (int m = 0; m < 8; m++) {
        e0 = __builtin_amdgcn_mfma_f32_16x16x32_bf16(afr[m], brg[0][m], e0, 0, 0, 0);
        e1 = __builtin_amdgcn_mfma_f32_16x16x32_bf16(afr[m], brg[1][m], e1, 0, 0, 0);
      }
#pragma unroll
      for (int r = 0; r < 4; r++) {
        int jr = jsub * 16 + q * 4 + r;       // local row in 64-row tile
        int jrow = j0 + jr;                   // global row
        // swizzled LDS read of adj pair (cols kc+2*l15, +1)
        f32x2 av = *(const f32x2*)((const char*)aj + jr * 512 +
                    (((w * 8 + (l15 >> 1)) ^ (jr & 7)) << 4) + ((l15 & 1) << 3));
        float x0 = (av[0] > 0.f) ? __expf(fminf(e0[r], 60.f)) : 0.f;
        float x1 = (av[1] > 0.f) ? __expf(fminf(e1[r], 60.f)) : 0.f;
        acc0 += x0; acc1 += x1;
        unsigned int pk = (unsigned int)f2bf(x0) | ((unsigned int)f2bf(x1) << 16);
        *(unsigned int*)(pun + ((bN + jrow) << 11) + kc + 2 * l15) = pk;
      }
    }
    __syncthreads();
  }
  acc0 += __shfl_xor(acc0, 16, 64); acc0 += __shfl_xor(acc0, 32, 64);
  acc1 += __shfl_xor(acc1, 16, 64); acc1 += __shfl_xor(acc1, 32, 64);
  if (lane < 16) {
    atomicAdd(&s_out[bN + kc + 2 * lane], acc0);
    atomicAdd(&s_out[bN + kc + 2 * lane + 1], acc1);
  }
}

// ---------- k1v: vt[b][d][j] = bf16(h[b][j][d] / s[j]) (R4-proven) ----------
__global__ __launch_bounds__(256) void k1v(const unsigned short* __restrict__ cat,
                                           const float* __restrict__ s,
                                           unsigned short* __restrict__ vt) {
  __shared__ unsigned short tile[64][136];
  __shared__ float rsv[64];
  const int t = threadIdx.x;
  const int b = blockIdx.y;
  const int nbase = blockIdx.x * 64;
  if (t < 64) rsv[t] = 1.f / s[(size_t)b * N_ + nbase + t];
#pragma unroll
  for (int k = 0; k < 4; k++) {
    int sI = t + 256 * k;
    int row = sI >> 4, part = sI & 15;
    *(short8*)&tile[row][part * 8] =
        *(const short8*)(cat + (((size_t)(b * N_ + nbase + row)) << 8) + 128 + part * 8);
  }
  __syncthreads();
#pragma unroll
  for (int k = 0; k < 4; k++) {
    int sI = t + 256 * k;
    int dd = sI >> 3, part = sI & 7;
    unsigned short tmp[8];
#pragma unroll
    for (int j = 0; j < 8; j++) {
      int jj = part * 8 + j;
      tmp[j] = f2bf(bf2f(tile[jj][dd]) * rsv[jj]);
    }
    *(short8*)(vt + (((size_t)(b * 128 + dd)) << 11) + nbase + part * 8) = *(short8*)tmp;
  }
}

// ---------- k3: h' = P_un @ V'; out = c*x + (1-c)*relu(h') ----------
// grid (N/64, B) = 256 blocks; 4 waves; wave w owns d-group [w*32, +32);
// i-tile 64 (halves vt re-read traffic vs i-tile 32), j-tile 64.
// 2x24KB dbuf, counted vmcnt(6) (R14 pattern, geometry-scaled).
__global__ __launch_bounds__(256) void k3(const unsigned short* __restrict__ pun,
                                          const unsigned short* __restrict__ vt,
                                          const float* __restrict__ x,
                                          const float* __restrict__ gw,
                                          const float* __restrict__ gb,
                                          float* __restrict__ out) {
  __shared__ char smem[2][24576];
  // per buffer: [0,8192): pa = P_un 64i x 64j   [8192,24576): vb = vt 128d x 64j
  const int t = threadIdx.x, w = t >> 6, lane = t & 63;
  const int q = lane >> 4, l15 = lane & 15;
  const int b = blockIdx.y, i0 = blockIdx.x * 64;
  const size_t bN = (size_t)b * N_;

  f32x4 acc[4][2];
#pragma unroll
  for (int ih = 0; ih < 4; ih++)
#pragma unroll
    for (int dh = 0; dh < 2; dh++) acc[ih][dh] = (f32x4){0.f, 0.f, 0.f, 0.f};

  // stage: 6 GLL/thread: pa 64 rows x 8 chunks (sI<512), vb 128 x 8 (sI>=512)
#define K3_STAGE(jtv, bufi) do { \
    const int j0_ = (jtv) * 64; \
    _Pragma("unroll") \
    for (int it = 0; it < 6; it++) { \
      int sI = it * 256 + t; \
      const unsigned short* g; \
      if (sI < 512) { \
        int row = sI >> 3, c = sI & 7; \
        g = pun + (((size_t)(bN + i0 + row)) << 11) + j0_ + ((c ^ (row & 7)) * 8); \
      } else { \
        int s2 = sI - 512; \
        int dd = s2 >> 3, c = s2 & 7; \
        g = vt + (((size_t)(b * 128 + dd)) << 11) + j0_ + ((c ^ (dd & 7)) * 8); \
      } \
      GLL(g, smem[bufi] + sI * 16); \
    } } while (0)

#define K3_COMPUTE(bufi) do { \
    unsigned short* pa = (unsigned short*)smem[bufi]; \
    unsigned short* vb = (unsigned short*)(smem[bufi] + 8192); \
    _Pragma("unroll") \
    for (int ks = 0; ks < 2; ks++) { \
      short8 af[4], bf[2]; \
      _Pragma("unroll") \
      for (int ih = 0; ih < 4; ih++) { \
        int m = ih * 16 + l15; \
        af[ih] = *(short8*)(pa + m * 64 + (((ks * 4 + q) ^ (m & 7)) * 8)); \
      } \
      _Pragma("unroll") \
      for (int dh = 0; dh < 2; dh++) { \
        int d = w * 32 + dh * 16 + l15; \
        bf[dh] = *(short8*)(vb + d * 64 + (((ks * 4 + q) ^ (d & 7)) * 8)); \
      } \
      _Pragma("unroll") \
      for (int ih = 0; ih < 4; ih++) { \
        acc[ih][0] = __builtin_amdgcn_mfma_f32_16x16x32_bf16(af[ih], bf[0], acc[ih][0], 0, 0, 0); \
        acc[ih][1] = __builtin_amdgcn_mfma_f32_16x16x32_bf16(af[ih], bf[1], acc[ih][1], 0, 0, 0); \
      } \
    } } while (0)

  K3_STAGE(0, 0);
  for (int jt = 0; jt < 31; jt++) {
    K3_STAGE(jt + 1, (jt + 1) & 1);
    asm volatile("s_waitcnt vmcnt(6)" ::: "memory");
    BARRIER();
    K3_COMPUTE(jt & 1);
    BARRIER();
  }
  asm volatile("s_waitcnt vmcnt(0)" ::: "memory");
  BARRIER();
  K3_COMPUTE(1);   // jt = 31
  __syncthreads(); // all reads done before epilogue reuses smem[0]
#undef K3_STAGE
#undef K3_COMPUTE

  // epilogue: relu -> LDS f32, gate, sigmoid, blend, store
  float* hs = (float*)smem[0];                     // 64 x 132 f32 = 33792 B
  float* co = (float*)((char*)smem[0] + 33792);    // 64 f32
#pragma unroll
  for (int ih = 0; ih < 4; ih++)
#pragma unroll
    for (int dh = 0; dh < 2; dh++)
#pragma unroll
      for (int r = 0; r < 4; r++) {
        int row = ih * 16 + q * 4 + r;
        int d = w * 32 + dh * 16 + l15;
        hs[row * 132 + d] = fmaxf(acc[ih][dh][r], 0.f);
      }
  __syncthreads();
  {
    int grow = t >> 2, sub = t & 3;   // 4 threads per row, 64 rows
    const float* xr = x + (((size_t)(bN + i0 + grow)) << 7);
    float z = 0.f;
#pragma unroll
    for (int k = 0; k < 32; k++) {
      int dd = sub + 4 * k;
      z += gw[dd] * xr[dd] + gw[128 + dd] * hs[grow * 132 + dd];
    }
    z += __shfl_xor(z, 1, 64);
    z += __shfl_xor(z, 2, 64);
    if (sub == 0) co[grow] = 1.f / (1.f + __expf(-(z + gb[0])));
  }
  __syncthreads();
#pragma unroll
  for (int kk = 0; kk < 8; kk++) {
    int id = kk * 256 + t;
    int row = id >> 5, c4 = id & 31;
    size_t g = (((size_t)(bN + i0 + row)) << 7) + c4 * 4;
    f32x4 xv = *(const f32x4*)(x + g);
    f32x4 hv = *(const f32x4*)(hs + row * 132 + c4 * 4);
    float cf = co[row];
    f32x4 o;
#pragma unroll
    for (int e = 0; e < 4; e++) o[e] = cf * xv[e] + (1.f - cf) * hv[e];
    *(f32x4*)(out + g) = o;
  }
}

extern "C" void kernel_launch(void* const* d_in, const int* in_sizes, int n_in,
                              void* d_out, int out_size, void* d_ws, size_t ws_size,
                              hipStream_t stream) {
  const float* x   = (const float*)d_in[0];
  const float* adj = (const float*)d_in[1];
  const float* Ww  = (const float*)d_in[2];
  const float* Wb  = (const float*)d_in[3];
  const float* A   = (const float*)d_in[4];
  const float* gw  = (const float*)d_in[5];
  const float* gb  = (const float*)d_in[6];
  float* out = (float*)d_out;
  char* ws = (char*)d_ws;

  unsigned short* cat = (unsigned short*)(ws + CAT_OFF);
  unsigned short* vt  = (unsigned short*)(ws + VT_OFF);
  unsigned short* pun = (unsigned short*)(ws + PUN_OFF);
  float* s  = (float*)(ws + S_OFF);
  unsigned short* Wb1 = (unsigned short*)(ws + WB_OFF);
  unsigned short* Abt = (unsigned short*)(ws + AT_OFF);

  hipMemsetAsync(s, 0, (size_t)B_ * N_ * sizeof(float), stream);
  k_cvt<<<64, 256, 0, stream>>>(Ww, A, Wb1, Abt);
  k1<<<(B_ * N_) / 64, 256, 0, stream>>>(x, Wb1, Wb, Abt, cat);
  k2<<<dim3(N_ / 128, 16, B_), 256, 0, stream>>>(cat, adj, pun, s);
  k1v<<<dim3(N_ / 64, B_), 256, 0, stream>>>(cat, s, vt);
  k3<<<dim3(N_ / 64, B_), 256, 0, stream>>>(pun, vt, x, gw, gb, out);
}